// Round 2
// baseline (219.758 us; speedup 1.0000x reference)
//
#include <hip/hip_runtime.h>

// NIGnet: X -> 64x [Y = X@W.T + b; X = (tanh(Y)+Y)/2] -> X@fW.T -> L2 normalize.
// Trans-pipe-bound (v_exp/v_rcp @ ~16cyc/wave64). This version:
//  - tanh via q = exp2(-|C*y|), C = 2*log2(e):  tanh(|y|) = 1 - 2*q*P(q),
//    P(q) ~ 1/(1+q) as a degree-6 poly (err ~7e-6)  => NO v_rcp in the loop.
//  - state kept pre-scaled by C (u = C*x) so the exp argument needs no mul.
//  - float2 ext-vector math over point-pairs => v_pk_fma_f32 codegen.
//  - layer loop unrolled x4 so s_load of W/b prefetches ahead.

typedef float f2 __attribute__((ext_vector_type(2)));

#define NP 4           // float4 chunks per thread = point-pairs per thread (8 points)
#define BLOCK 256

__global__ __launch_bounds__(BLOCK) void nig_kernel(
    const float* __restrict__ X_in,
    const float* __restrict__ Ws,    // [L,2,2]
    const float* __restrict__ bs,    // [L,2]
    const float* __restrict__ fW,    // [2,2]
    float* __restrict__ out,
    int M,                           // float4 chunks = N/2
    int L)
{
    const int tid = blockIdx.x * blockDim.x + threadIdx.x;
    const int nthreads = gridDim.x * blockDim.x;
    const float4* __restrict__ in4 = (const float4*)X_in;
    float4* __restrict__ out4 = (float4*)out;

    const float C     = 2.8853900817779268f;   // 2*log2(e)
    const float halfC = 1.4426950408889634f;

    // X0 = component-0 of (pointA, pointB); X1 = component-1. State scaled by C.
    f2 X0[NP], X1[NP];
    int idx[NP]; bool ok[NP];
    #pragma unroll
    for (int j = 0; j < NP; ++j) {
        idx[j] = tid + j * nthreads;
        ok[j] = idx[j] < M;
        float4 v = ok[j] ? in4[idx[j]] : make_float4(0.f, 0.f, 0.f, 0.f);
        X0[j] = (f2){v.x, v.z} * C;
        X1[j] = (f2){v.y, v.w} * C;
    }

    // P(q) ~ 1/(1+q) on [0,1] (Chebyshev-truncated deg 6, |err| < ~7e-6)
    const float p0 = 0.999992f,  p1 = -0.999210f, p2 = 0.986366f,
                p3 = -0.907073f, p4 = 0.675347f,  p5 = -0.329296f,
                p6 = 0.0738812f;

    #pragma unroll 4
    for (int l = 0; l < L; ++l) {
        const float4 w = ((const float4*)Ws)[l];   // uniform -> s_load
        const float2 b = ((const float2*)bs)[l];
        const float cb0 = C * b.x, cb1 = C * b.y;
        #pragma unroll
        for (int j = 0; j < NP; ++j) {
            f2 y0 = w.x * X0[j] + w.y * X1[j] + cb0;   // = C*(Wx+b), pk_fma
            f2 y1 = w.z * X0[j] + w.w * X1[j] + cb1;
            f2 q0, q1;
            q0.x = __builtin_amdgcn_exp2f(-__builtin_fabsf(y0.x));
            q0.y = __builtin_amdgcn_exp2f(-__builtin_fabsf(y0.y));
            q1.x = __builtin_amdgcn_exp2f(-__builtin_fabsf(y1.x));
            q1.y = __builtin_amdgcn_exp2f(-__builtin_fabsf(y1.y));
            f2 P0 = p6;
            P0 = P0 * q0 + p5; P0 = P0 * q0 + p4; P0 = P0 * q0 + p3;
            P0 = P0 * q0 + p2; P0 = P0 * q0 + p1; P0 = P0 * q0 + p0;
            f2 P1 = p6;
            P1 = P1 * q1 + p5; P1 = P1 * q1 + p4; P1 = P1 * q1 + p3;
            P1 = P1 * q1 + p2; P1 = P1 * q1 + p1; P1 = P1 * q1 + p0;
            f2 m0 = q0 * P0, m1 = q1 * P1;            // q/(1+q)
            f2 h0 = halfC - C * m0;                    // C*(0.5 - m) >= 0, fma
            f2 h1 = halfC - C * m1;
            f2 s0, s1;                                 // restore sign: v_bfi
            s0.x = __builtin_copysignf(h0.x, y0.x);
            s0.y = __builtin_copysignf(h0.y, y0.y);
            s1.x = __builtin_copysignf(h1.x, y1.x);
            s1.y = __builtin_copysignf(h1.y, y1.y);
            X0[j] = 0.5f * y0 + s0;                    // u' = C*(y+tanh(y))/2
            X1[j] = 0.5f * y1 + s1;
        }
    }

    // Final linear (un-scale by 1/C folded into fW) + L2 normalize.
    const float ic = 0.34657359027997264f;             // 1/C = ln(2)/2
    const float g0 = fW[0] * ic, g1 = fW[1] * ic, g2 = fW[2] * ic, g3 = fW[3] * ic;

    #pragma unroll
    for (int j = 0; j < NP; ++j) {
        if (!ok[j]) continue;
        f2 z0 = g0 * X0[j] + g1 * X1[j];
        f2 z1 = g2 * X0[j] + g3 * X1[j];
        f2 s  = z0 * z0 + z1 * z1;
        float na = __builtin_amdgcn_sqrtf(s.x);
        float nb = __builtin_amdgcn_sqrtf(s.y);
        float ia = __builtin_amdgcn_rcpf(fmaxf(na, 1e-12f));
        float ib = __builtin_amdgcn_rcpf(fmaxf(nb, 1e-12f));
        float4 o;
        o.x = z0.x * ia; o.y = z1.x * ia;
        o.z = z0.y * ib; o.w = z1.y * ib;
        out4[idx[j]] = o;
    }
}

extern "C" void kernel_launch(void* const* d_in, const int* in_sizes, int n_in,
                              void* d_out, int out_size, void* d_ws, size_t ws_size,
                              hipStream_t stream) {
    // 0=T(unused), 1=closed_manifold [N,2], 2=Ws [L,2,2], 3=bs [L,2], 4=final_W [2,2]
    const float* X  = (const float*)d_in[1];
    const float* Ws = (const float*)d_in[2];
    const float* bs = (const float*)d_in[3];
    const float* fW = (const float*)d_in[4];
    float* out = (float*)d_out;

    const int L = in_sizes[2] / 4;
    const int M = in_sizes[1] / 4;
    const int threads = (M + NP - 1) / NP;
    const int grid = (threads + BLOCK - 1) / BLOCK;

    nig_kernel<<<grid, BLOCK, 0, stream>>>(X, Ws, bs, fW, out, M, L);
}

// Round 4
// 190.490 us; speedup vs baseline: 1.1537x; 1.1537x over previous
//
#include <hip/hip_runtime.h>

// NIGnet: X -> 64x [Y = X@W.T + b; X = (tanh(Y)+Y)/2] -> X@fW.T -> L2 normalize.
// Calibration (R1-R3): scalar fp32 VALU = 2 cyc/wave64; trans (v_exp/v_rcp) ~8-11 cyc;
// packed fp32 is NOT faster on CDNA4 (157.3 TF peak == unpacked rate) — stay scalar.
// This version vs R1 (143 us):
//  - state pre-scaled by C = 2*log2(e):  u = C*x, y_u = W@u + C*b, e = exp2(y_u)
//    directly (no per-point mul before exp). tanh = 1 - 2/(e+1) with exact
//    saturation (exp2->inf => rcp->0; exp2->0 => rcp(1)=1). 10 full + 4 trans /pt.
//  - update fused: u' = (y_u + C*tanh)/2 = fma(-C, r, fma(0.5, y_u, C/2)).
//  - manual next-layer W/b prefetch + unroll 2 to hide s_load latency at layer head.
//  - final 1/C un-scale skipped: row L2-normalize cancels any uniform positive scale.

#define KPT 8          // points per thread (4 float4 chunks) — ILP for trans latency
#define BLOCK 256

__global__ __launch_bounds__(BLOCK) void nig_kernel(
    const float* __restrict__ X_in,
    const float* __restrict__ Ws,    // [L,2,2] row-major
    const float* __restrict__ bs,    // [L,2]
    const float* __restrict__ fW,    // [2,2]
    float* __restrict__ out,
    int M,                           // float4 chunks = N/2
    int L)
{
    const int tid = blockIdx.x * blockDim.x + threadIdx.x;
    const int nthreads = gridDim.x * blockDim.x;
    const float4* __restrict__ in4 = (const float4*)X_in;
    float4* __restrict__ out4 = (float4*)out;

    const float C     = 2.8853900817779268f;   // 2*log2(e)
    const float halfC = 1.4426950408889634f;   // C/2

    // u0 = comp-0, u1 = comp-1, state scaled by C.
    float u0[KPT], u1[KPT];
    int idx[KPT / 2]; bool ok[KPT / 2];
    #pragma unroll
    for (int j = 0; j < KPT / 2; ++j) {
        idx[j] = tid + j * nthreads;
        ok[j] = idx[j] < M;
        float4 v = ok[j] ? in4[idx[j]] : make_float4(0.f, 0.f, 0.f, 0.f);
        u0[2 * j]     = v.x * C; u1[2 * j]     = v.y * C;
        u0[2 * j + 1] = v.z * C; u1[2 * j + 1] = v.w * C;
    }

    // Prefetch layer 0 weights (uniform -> s_load through scalar cache).
    float4 w = ((const float4*)Ws)[0];
    float2 b = ((const float2*)bs)[0];

    #pragma unroll 2
    for (int l = 0; l < L; ++l) {
        // Prefetch next layer while computing this one (clamped index, uniform).
        const int ln = (l + 1 < L) ? (l + 1) : l;
        float4 wn = ((const float4*)Ws)[ln];
        float2 bn = ((const float2*)bs)[ln];

        const float cb0 = C * b.x;
        const float cb1 = C * b.y;
        #pragma unroll
        for (int k = 0; k < KPT; ++k) {
            float y0 = fmaf(w.x, u0[k], fmaf(w.y, u1[k], cb0));  // C*(Wx+b)
            float y1 = fmaf(w.z, u0[k], fmaf(w.w, u1[k], cb1));
            float e0 = __builtin_amdgcn_exp2f(y0);               // = exp(2*y)
            float e1 = __builtin_amdgcn_exp2f(y1);
            float r0 = __builtin_amdgcn_rcpf(e0 + 1.0f);         // 1/(e^{2y}+1)
            float r1 = __builtin_amdgcn_rcpf(e1 + 1.0f);
            // u' = 0.5*y_u + C*(0.5 - r)   (tanh = 1 - 2r)
            u0[k] = fmaf(-C, r0, fmaf(0.5f, y0, halfC));
            u1[k] = fmaf(-C, r1, fmaf(0.5f, y1, halfC));
        }
        w = wn; b = bn;
    }

    // Final linear + L2 normalize. Uniform scale C cancels in normalization.
    const float g0 = fW[0], g1 = fW[1], g2 = fW[2], g3 = fW[3];

    #pragma unroll
    for (int j = 0; j < KPT / 2; ++j) {
        if (!ok[j]) continue;
        float4 o;
        #pragma unroll
        for (int h = 0; h < 2; ++h) {
            const int k = 2 * j + h;
            float z0 = fmaf(g0, u0[k], g1 * u1[k]);
            float z1 = fmaf(g2, u0[k], g3 * u1[k]);
            float s  = fmaf(z0, z0, z1 * z1);
            float n  = __builtin_amdgcn_sqrtf(s);
            float iv = __builtin_amdgcn_rcpf(fmaxf(n, 1e-12f));
            if (h == 0) { o.x = z0 * iv; o.y = z1 * iv; }
            else        { o.z = z0 * iv; o.w = z1 * iv; }
        }
        out4[idx[j]] = o;
    }
}

extern "C" void kernel_launch(void* const* d_in, const int* in_sizes, int n_in,
                              void* d_out, int out_size, void* d_ws, size_t ws_size,
                              hipStream_t stream) {
    // 0=T(unused), 1=closed_manifold [N,2], 2=Ws [L,2,2], 3=bs [L,2], 4=final_W [2,2]
    const float* X  = (const float*)d_in[1];
    const float* Ws = (const float*)d_in[2];
    const float* bs = (const float*)d_in[3];
    const float* fW = (const float*)d_in[4];
    float* out = (float*)d_out;

    const int L = in_sizes[2] / 4;
    const int M = in_sizes[1] / 4;
    const int threads = (M + (KPT / 2) - 1) / (KPT / 2);
    const int grid = (threads + BLOCK - 1) / BLOCK;

    nig_kernel<<<grid, BLOCK, 0, stream>>>(X, Ws, bs, fW, out, M, L);
}

// Round 5
// 190.278 us; speedup vs baseline: 1.1549x; 1.0011x over previous
//
#include <hip/hip_runtime.h>

// NIGnet: X -> 64x [Y = X@W.T + b; X = (tanh(Y)+Y)/2] -> X@fW.T -> L2 normalize.
// Calibration (R1-R4): full-rate fp32 = 2 cyc/wave64; trans (v_exp/v_rcp) issue ~8 cyc
// (quarter rate); packed fp32 adds nothing on CDNA4 (157.3 TF == unpacked rate).
// R4 fit: T_eff 12.7 vs T_issue ~9.5 => ~22% stall cycles. Cause: VGPR_Count=24 —
// only ~8 scratch regs over the 16 state regs, so the compiler serializes the
// exp->add->rcp chains instead of overlapping 8 points.
// R5: phase-split inner loop (all y, then all exp, then all d=e+1, then all rcp,
// then all updates) with explicit arrays + __launch_bounds__(256,8) (VGPR cap 64)
// so 16 trans results stay live and the trans pipe runs back-to-back.

#define KPT 8          // points per thread (4 float4 chunks)
#define BLOCK 256

__global__ __launch_bounds__(BLOCK, 8) void nig_kernel(
    const float* __restrict__ X_in,
    const float* __restrict__ Ws,    // [L,2,2] row-major
    const float* __restrict__ bs,    // [L,2]
    const float* __restrict__ fW,    // [2,2]
    float* __restrict__ out,
    int M,                           // float4 chunks = N/2
    int L)
{
    const int tid = blockIdx.x * blockDim.x + threadIdx.x;
    const int nthreads = gridDim.x * blockDim.x;
    const float4* __restrict__ in4 = (const float4*)X_in;
    float4* __restrict__ out4 = (float4*)out;

    const float C     = 2.8853900817779268f;   // 2*log2(e)
    const float halfC = 1.4426950408889634f;   // C/2

    float u0[KPT], u1[KPT];
    int idx[KPT / 2]; bool ok[KPT / 2];
    #pragma unroll
    for (int j = 0; j < KPT / 2; ++j) {
        idx[j] = tid + j * nthreads;
        ok[j] = idx[j] < M;
        float4 v = ok[j] ? in4[idx[j]] : make_float4(0.f, 0.f, 0.f, 0.f);
        u0[2 * j]     = v.x * C; u1[2 * j]     = v.y * C;
        u0[2 * j + 1] = v.z * C; u1[2 * j + 1] = v.w * C;
    }

    float4 w = ((const float4*)Ws)[0];
    float2 b = ((const float2*)bs)[0];

    float y0[KPT], y1[KPT];    // C*(Wx+b)
    float d0[KPT], d1[KPT];    // exp2(y)+1

    #pragma unroll 2
    for (int l = 0; l < L; ++l) {
        const int ln = (l + 1 < L) ? (l + 1) : l;
        float4 wn = ((const float4*)Ws)[ln];   // prefetch next layer (s_load)
        float2 bn = ((const float2*)bs)[ln];

        const float cb0 = C * b.x;
        const float cb1 = C * b.y;

        // Phase 1: all linears (16 indep fma chains of 2)
        #pragma unroll
        for (int k = 0; k < KPT; ++k) {
            y0[k] = fmaf(w.x, u0[k], fmaf(w.y, u1[k], cb0));
            y1[k] = fmaf(w.z, u0[k], fmaf(w.w, u1[k], cb1));
        }
        // Phase 2: all 16 exps back-to-back into the trans pipe
        #pragma unroll
        for (int k = 0; k < KPT; ++k) {
            d0[k] = __builtin_amdgcn_exp2f(y0[k]);
            d1[k] = __builtin_amdgcn_exp2f(y1[k]);
        }
        // Phase 3: all +1 (full-rate, overlaps exp drain)
        #pragma unroll
        for (int k = 0; k < KPT; ++k) {
            d0[k] += 1.0f;
            d1[k] += 1.0f;
        }
        // Phase 4: all 16 rcps + fused update u' = 0.5*y + C*(0.5 - r)
        #pragma unroll
        for (int k = 0; k < KPT; ++k) {
            float r0 = __builtin_amdgcn_rcpf(d0[k]);
            float r1 = __builtin_amdgcn_rcpf(d1[k]);
            u0[k] = fmaf(-C, r0, fmaf(0.5f, y0[k], halfC));
            u1[k] = fmaf(-C, r1, fmaf(0.5f, y1[k], halfC));
        }
        w = wn; b = bn;
    }

    // Final linear + L2 normalize (uniform scale C cancels in normalization).
    const float g0 = fW[0], g1 = fW[1], g2 = fW[2], g3 = fW[3];

    #pragma unroll
    for (int j = 0; j < KPT / 2; ++j) {
        if (!ok[j]) continue;
        float4 o;
        #pragma unroll
        for (int h = 0; h < 2; ++h) {
            const int k = 2 * j + h;
            float z0 = fmaf(g0, u0[k], g1 * u1[k]);
            float z1 = fmaf(g2, u0[k], g3 * u1[k]);
            float s  = fmaf(z0, z0, z1 * z1);
            float n  = __builtin_amdgcn_sqrtf(s);
            float iv = __builtin_amdgcn_rcpf(fmaxf(n, 1e-12f));
            if (h == 0) { o.x = z0 * iv; o.y = z1 * iv; }
            else        { o.z = z0 * iv; o.w = z1 * iv; }
        }
        out4[idx[j]] = o;
    }
}

extern "C" void kernel_launch(void* const* d_in, const int* in_sizes, int n_in,
                              void* d_out, int out_size, void* d_ws, size_t ws_size,
                              hipStream_t stream) {
    // 0=T(unused), 1=closed_manifold [N,2], 2=Ws [L,2,2], 3=bs [L,2], 4=final_W [2,2]
    const float* X  = (const float*)d_in[1];
    const float* Ws = (const float*)d_in[2];
    const float* bs = (const float*)d_in[3];
    const float* fW = (const float*)d_in[4];
    float* out = (float*)d_out;

    const int L = in_sizes[2] / 4;
    const int M = in_sizes[1] / 4;
    const int threads = (M + (KPT / 2) - 1) / (KPT / 2);
    const int grid = (threads + BLOCK - 1) / BLOCK;

    nig_kernel<<<grid, BLOCK, 0, stream>>>(X, Ws, bs, fW, out, M, L);
}